// Round 1
// baseline (756.992 us; speedup 1.0000x reference)
//
#include <hip/hip_runtime.h>

#define N_NODES   50000
#define N_EDGES   1600000
#define DDIM      64
#define N_GRAPHS  512
#define N_CLASSES 53
#define ITERS     3

// broadcast value from lane l (compile-time after unroll) -> wave-uniform scalar
__device__ __forceinline__ float bcast_lane(float v, int l) {
  return __uint_as_float(__builtin_amdgcn_readlane(__float_as_uint(v), l));
}

// h[node][d] = emb[pkt[node]][d], float4-vectorized
__global__ void embed_kernel(const int* __restrict__ pkt, const float4* __restrict__ emb,
                             float4* __restrict__ h) {
  int idx = blockIdx.x * 256 + threadIdx.x;           // over N_NODES*16 float4s
  if (idx >= N_NODES * 16) return;
  int node = idx >> 4;
  h[idx] = emb[(size_t)pkt[node] * 16 + (idx & 15)];
}

__global__ void hist_kernel(const int* __restrict__ idx, int* __restrict__ counts, int n) {
  int i = blockIdx.x * 256 + threadIdx.x;
  if (i < n) atomicAdd(&counts[idx[i]], 1);
}

// single-block exclusive scan; offs[n] = total; optional cursor copy
__global__ void scan_kernel(const int* __restrict__ counts, int* __restrict__ offs,
                            int* __restrict__ cursor, int n) {
  __shared__ int wsum[16];
  __shared__ int carry;
  int tid = threadIdx.x;               // 1024 threads
  if (tid == 0) carry = 0;
  __syncthreads();
  for (int base = 0; base < n; base += 1024) {
    int i = base + tid;
    int v = (i < n) ? counts[i] : 0;
    int x = v;
    #pragma unroll
    for (int off = 1; off < 64; off <<= 1) {
      int y = __shfl_up(x, off);
      if ((tid & 63) >= off) x += y;
    }
    int w = tid >> 6;
    if ((tid & 63) == 63) wsum[w] = x;
    __syncthreads();
    int woff = 0;
    for (int k = 0; k < w; ++k) woff += wsum[k];
    int incl = x + woff + carry;
    if (i < n) {
      offs[i] = incl - v;
      if (cursor) cursor[i] = incl - v;
    }
    __syncthreads();                   // everyone has read old carry
    if (tid == 1023) carry = incl;
    __syncthreads();
  }
  if (tid == 0) offs[n] = carry;
}

__global__ void scatter_kernel(const int* __restrict__ src, const int* __restrict__ dst,
                               int* __restrict__ cursor, int* __restrict__ csr) {
  int i = blockIdx.x * 256 + threadIdx.x;
  if (i < N_EDGES) {
    int p = atomicAdd(&cursor[dst[i]], 1);
    csr[p] = src[i];
  }
}

// x[v] = (1+eps)*h[v] + sum_{u in in-nbrs(v)} h[u]; wave per node, lane = feature
__global__ void aggregate_kernel(const float* __restrict__ h, const int* __restrict__ offs,
                                 const int* __restrict__ csr, const float* __restrict__ epsp,
                                 float* __restrict__ x) {
  int node = blockIdx.x * 4 + (threadIdx.x >> 6);
  if (node >= N_NODES) return;
  int lane = threadIdx.x & 63;
  int beg = offs[node], end = offs[node + 1];
  float acc = (1.0f + epsp[0]) * h[(size_t)node * DDIM + lane];
  int e = beg;
  for (; e + 4 <= end; e += 4) {      // unroll-4 for load ILP (latency-bound gather)
    int u0 = csr[e + 0], u1 = csr[e + 1], u2 = csr[e + 2], u3 = csr[e + 3];
    float a0 = h[(size_t)u0 * DDIM + lane];
    float a1 = h[(size_t)u1 * DDIM + lane];
    float a2 = h[(size_t)u2 * DDIM + lane];
    float a3 = h[(size_t)u3 * DDIM + lane];
    acc += (a0 + a1) + (a2 + a3);
  }
  for (; e < end; ++e) acc += h[(size_t)csr[e] * DDIM + lane];
  x[(size_t)node * DDIM + lane] = acc;
}

// one 64x64 Linear+ReLU with weight column resident in 64 VGPRs (static-indexed)
#define LAYER(v, w, bias, outv)                                     \
  {                                                                 \
    float y0 = (bias), y1 = 0.f, y2 = 0.f, y3 = 0.f;                \
    _Pragma("unroll")                                               \
    for (int d = 0; d < 64; d += 4) {                               \
      y0 = fmaf(bcast_lane(v, d + 0), w[d + 0], y0);                \
      y1 = fmaf(bcast_lane(v, d + 1), w[d + 1], y1);                \
      y2 = fmaf(bcast_lane(v, d + 2), w[d + 2], y2);                \
      y3 = fmaf(bcast_lane(v, d + 3), w[d + 3], y3);                \
    }                                                               \
    outv = fmaxf((y0 + y1) + (y2 + y3), 0.f);                       \
  }

// fused 3-layer MLP, wave per row (lane = output feature), + BN partial stats
__global__ __launch_bounds__(256) void mlp_kernel(
    const float* __restrict__ xin, float* __restrict__ xout,
    const float* __restrict__ W1, const float* __restrict__ b1,
    const float* __restrict__ W2, const float* __restrict__ b2,
    const float* __restrict__ W3, const float* __restrict__ b3,
    float* __restrict__ bnsum, float* __restrict__ bnsq) {
  const int lane = threadIdx.x & 63;
  const int wave = blockIdx.x * 4 + (threadIdx.x >> 6);
  const int nwaves = gridDim.x * 4;
  float w1[64], w2[64], w3[64];        // W*[d][lane] columns, 192 VGPRs
  #pragma unroll
  for (int d = 0; d < 64; ++d) {
    w1[d] = W1[d * 64 + lane];
    w2[d] = W2[d * 64 + lane];
    w3[d] = W3[d * 64 + lane];
  }
  const float bb1 = b1[lane], bb2 = b2[lane], bb3 = b3[lane];
  float s = 0.f, sq = 0.f;
  for (int row = wave; row < N_NODES; row += nwaves) {
    float v = xin[(size_t)row * DDIM + lane];
    float t;
    LAYER(v, w1, bb1, t); v = t;
    LAYER(v, w2, bb2, t); v = t;
    LAYER(v, w3, bb3, t); v = t;
    xout[(size_t)row * DDIM + lane] = v;
    s += v;
    sq += v * v;
  }
  atomicAdd(&bnsum[lane], s);
  atomicAdd(&bnsq[lane], sq);
}

__global__ void bn_finalize_kernel(float* __restrict__ bnsum, float* __restrict__ bnsq,
                                   float* __restrict__ stats) {
  int lane = threadIdx.x;              // 64 threads
  const float invN = 1.0f / N_NODES;
  float m = bnsum[lane] * invN;
  float var = bnsq[lane] * invN - m * m;
  stats[lane] = m;
  stats[64 + lane] = 1.0f / sqrtf(var + 1e-5f);
  bnsum[lane] = 0.f;                   // ready for next iteration
  bnsq[lane] = 0.f;
}

// BN-apply -> h, plus atomic-free graph pooling (block per graph; graph_ids sorted)
__global__ void norm_pool_kernel(const float* __restrict__ x, float* __restrict__ h,
                                 float* __restrict__ pooled, const int* __restrict__ goff,
                                 const float* __restrict__ stats, const float* __restrict__ gamma,
                                 const float* __restrict__ beta, int iter) {
  int g = blockIdx.x;
  int lane = threadIdx.x & 63;
  int wave = threadIdx.x >> 6;
  float mean = stats[lane];
  float inv = stats[64 + lane];
  float gm = gamma[lane] * inv;
  float bt = beta[lane] - mean * gm;   // h = gm*v + bt
  int rbeg = goff[g], rend = goff[g + 1];
  float acc = 0.f;
  for (int r = rbeg + wave; r < rend; r += 4) {
    float v = fmaf(x[(size_t)r * DDIM + lane], gm, bt);
    h[(size_t)r * DDIM + lane] = v;
    acc += v;
  }
  __shared__ float red[4][64];
  red[wave][lane] = acc;
  __syncthreads();
  if (wave == 0) {
    pooled[(size_t)g * (ITERS * DDIM) + iter * DDIM + lane] =
        red[0][lane] + red[1][lane] + red[2][lane] + red[3][lane];
  }
}

__global__ void classifier_kernel(const float* __restrict__ pooled, const float* __restrict__ Wc,
                                  const float* __restrict__ bc, float* __restrict__ out) {
  int g = blockIdx.x;
  int c = threadIdx.x;
  if (c >= N_CLASSES) return;
  float acc = bc[c];
  #pragma unroll 4
  for (int k = 0; k < ITERS * DDIM; ++k)
    acc = fmaf(pooled[(size_t)g * (ITERS * DDIM) + k], Wc[k * N_CLASSES + c], acc);
  out[(size_t)g * N_CLASSES + c] = acc;
}

extern "C" void kernel_launch(void* const* d_in, const int* in_sizes, int n_in,
                              void* d_out, int out_size, void* d_ws, size_t ws_size,
                              hipStream_t stream) {
  const int*   pkt   = (const int*)d_in[0];
  const int*   src   = (const int*)d_in[1];
  const int*   dst   = (const int*)d_in[2];
  const int*   gids  = (const int*)d_in[3];
  const float* emb   = (const float*)d_in[4];
  const float* eps   = (const float*)d_in[5];
  const float* W1    = (const float*)d_in[6];
  const float* b1    = (const float*)d_in[7];
  const float* W2    = (const float*)d_in[8];
  const float* b2    = (const float*)d_in[9];
  const float* W3    = (const float*)d_in[10];
  const float* b3    = (const float*)d_in[11];
  const float* gamma = (const float*)d_in[12];
  const float* beta  = (const float*)d_in[13];
  const float* Wc    = (const float*)d_in[14];
  const float* bc    = (const float*)d_in[15];
  float* out = (float*)d_out;

  char* p = (char*)d_ws;
  auto alloc = [&](size_t bytes) {
    char* r = p;
    p += (bytes + 255) & ~(size_t)255;
    return r;
  };
  float* h      = (float*)alloc((size_t)N_NODES * DDIM * 4);
  float* x      = (float*)alloc((size_t)N_NODES * DDIM * 4);
  int*   csr    = (int*)alloc((size_t)N_EDGES * 4);
  int*   offs   = (int*)alloc((size_t)(N_NODES + 1) * 4);
  int*   cursor = (int*)alloc((size_t)N_NODES * 4);
  int*   goff   = (int*)alloc((size_t)(N_GRAPHS + 1) * 4);
  float* pooled = (float*)alloc((size_t)N_GRAPHS * ITERS * DDIM * 4);
  float* stats  = (float*)alloc(128 * 4);
  // contiguous zero region: counts | gcnt | bnsum | bnsq
  size_t zbytes = (size_t)N_NODES * 4 + (size_t)N_GRAPHS * 4 + 512;
  char*  zbase  = alloc(zbytes);
  int*   counts = (int*)zbase;
  int*   gcnt   = counts + N_NODES;
  float* bnsum  = (float*)(gcnt + N_GRAPHS);
  float* bnsq   = bnsum + 64;

  hipMemsetAsync(zbase, 0, zbytes, stream);

  embed_kernel<<<(N_NODES * 16 + 255) / 256, 256, 0, stream>>>(pkt, (const float4*)emb,
                                                               (float4*)h);
  hist_kernel<<<(N_EDGES + 255) / 256, 256, 0, stream>>>(dst, counts, N_EDGES);
  hist_kernel<<<(N_NODES + 255) / 256, 256, 0, stream>>>(gids, gcnt, N_NODES);
  scan_kernel<<<1, 1024, 0, stream>>>(counts, offs, cursor, N_NODES);
  scan_kernel<<<1, 1024, 0, stream>>>(gcnt, goff, nullptr, N_GRAPHS);
  scatter_kernel<<<(N_EDGES + 255) / 256, 256, 0, stream>>>(src, dst, cursor, csr);

  for (int it = 0; it < ITERS; ++it) {
    aggregate_kernel<<<(N_NODES + 3) / 4, 256, 0, stream>>>(h, offs, csr, eps, x);
    mlp_kernel<<<512, 256, 0, stream>>>(x, x, W1, b1, W2, b2, W3, b3, bnsum, bnsq);
    bn_finalize_kernel<<<1, 64, 0, stream>>>(bnsum, bnsq, stats);
    norm_pool_kernel<<<N_GRAPHS, 256, 0, stream>>>(x, h, pooled, goff, stats, gamma, beta, it);
  }
  classifier_kernel<<<N_GRAPHS, 64, 0, stream>>>(pooled, Wc, bc, out);
}